// Round 9
// baseline (217.109 us; speedup 1.0000x reference)
//
#include <hip/hip_runtime.h>
#include <hip/hip_bf16.h>
#include <stdint.h>

// MetaAttention: x[8,1024,768] f32, Wq/Wk/Wv/Wo[768,768] f32 -> out[8,1024,768] f32
// Pipeline (4 kernels, round-7 structure):
//   convert: x->xb, [Wq;Wk;Wv]->wqkv (d_out head scratch), Wo->wob (d_ws tail).
//   gemm_qkv: fused NT GEMM M=8192 N=2304 K=768, glds + XOR swizzle,
//             *** 128x256 tile (wave=64x128, 4x8 acc) -> 2x MFMA per barrier ***
//             q pre-scaled by 0.125*log2(e); v stored per-head transposed vt.
//   attn: (b,h) x 64 q-rows per block (grid 1536, 6 blocks/CU); single-buffered
//         K/V; S'=K Q'^T; P=exp2(S') in regs feeding PV B-frags; vect ALIASES q.
//   gemm_out: out = vect Wo^T, 64x128 tile (768 blocks), pure glds.
// d_ws (bf16): q/vect | k | vt | wob.

typedef __bf16 bf16x8 __attribute__((ext_vector_type(8)));
typedef __bf16 bf16x4 __attribute__((ext_vector_type(4)));
typedef float f32x4 __attribute__((ext_vector_type(4)));

#define GAS __attribute__((address_space(1)))
#define LAS __attribute__((address_space(3)))

__device__ __forceinline__ void glds16(const short* gp, short* lp) {
  __builtin_amdgcn_global_load_lds((const GAS void*)gp, (LAS void*)lp, 16, 0, 0);
}

__device__ __forceinline__ float fast_exp2(float x) {
#if __has_builtin(__builtin_amdgcn_exp2f)
  return __builtin_amdgcn_exp2f(x);
#else
  return __expf(x * 0.6931471805599453f);
#endif
}

__device__ __forceinline__ short bfbits(float f) {
  __bf16 b = (__bf16)f;                  // fptrunc RNE -> HW cvt
  union { __bf16 b; short s; } cv; cv.b = b;
  return cv.s;
}

__device__ __forceinline__ void stage8_f32(const float* __restrict__ src, short* dst) {
  float4 f0 = ((const float4*)src)[0];
  float4 f1 = ((const float4*)src)[1];
  bf16x8 t;
  t[0] = (__bf16)f0.x; t[1] = (__bf16)f0.y; t[2] = (__bf16)f0.z; t[3] = (__bf16)f0.w;
  t[4] = (__bf16)f1.x; t[5] = (__bf16)f1.y; t[6] = (__bf16)f1.z; t[7] = (__bf16)f1.w;
  *(bf16x8*)dst = t;
}

// --------------------------------------------------------------------------
// fp32 -> bf16 bulk conversion, flat exact grid: 1056 blocks x 1024 units.
// --------------------------------------------------------------------------
__global__ __launch_bounds__(256) void convert_kernel(
    const float* __restrict__ x, const float* __restrict__ Wq,
    const float* __restrict__ Wk, const float* __restrict__ Wv,
    const float* __restrict__ Wo,
    short* __restrict__ xb, short* __restrict__ wqkv, short* __restrict__ wob) {
  int u0 = blockIdx.x * 1024 + threadIdx.x;
#pragma unroll
  for (int i = 0; i < 4; ++i) {
    int u = u0 + i * 256;
    const float* src; short* dst;
    if (u < 786432) { src = x + (size_t)u * 8; dst = xb + (size_t)u * 8; }
    else if (u < 1007616) {
      int r = u - 786432;
      int wsel = r / 73728, off = r % 73728;
      const float* W = (wsel == 0) ? Wq : (wsel == 1) ? Wk : Wv;
      src = W + (size_t)off * 8;
      dst = wqkv + (size_t)r * 8;
    } else {
      int r = u - 1007616;
      src = Wo + (size_t)r * 8; dst = wob + (size_t)r * 8;
    }
    stage8_f32(src, dst);
  }
}

// --------------------------------------------------------------------------
// Fused QKV NT GEMM, 128x256 tile, BK=64, glds + XOR chunk swizzle.
// 4 waves, wave (wr,wc): rows wr*64..+64, cols wc*128..+128 -> acc[4][8].
// 64 MFMA per wave per K-step (2x the 128x128 tile) -> barrier drain amortized.
// q output pre-scaled by 0.125*log2(e); v stored per-head transposed.
// --------------------------------------------------------------------------
__global__ __launch_bounds__(256) void gemm_qkv(
    const short* __restrict__ xb, const short* __restrict__ wqkv,
    short* __restrict__ q, short* __restrict__ k, short* __restrict__ vt) {
  const int m0 = blockIdx.x * 128;
  const int by = blockIdx.y;               // 0..8, 256 cols each
  const int n0g = by * 256;
  const int tid = threadIdx.x;
  const int w = tid >> 6, lane = tid & 63, l16 = lane & 15, quad = lane >> 4;
  const int wr = w >> 1, wc = w & 1;

  __shared__ short sA[128 * 64];   // 16 KB
  __shared__ short sB[256 * 64];   // 32 KB

  f32x4 acc[4][8];
#pragma unroll
  for (int i = 0; i < 4; ++i)
#pragma unroll
    for (int j = 0; j < 8; ++j) acc[i][j] = (f32x4){0.f, 0.f, 0.f, 0.f};

  for (int k0 = 0; k0 < 768; k0 += 64) {
    __syncthreads();
    const short* Ab = xb + (size_t)m0 * 768 + k0;
    const short* Bb = wqkv + (size_t)n0g * 768 + k0;
    // stage A: 1024 chunks (4/thread)
#pragma unroll
    for (int p = 0; p < 4; ++p) {
      int lin = (w * 4 + p) * 64 + lane;
      int row = lin >> 3;
      int cs = ((lin & 7) ^ (row & 7)) * 8;
      glds16(Ab + (size_t)row * 768 + cs, &sA[lin * 8]);
    }
    // stage B: 2048 chunks (8/thread)
#pragma unroll
    for (int p = 0; p < 8; ++p) {
      int lin = (w * 8 + p) * 64 + lane;
      int row = lin >> 3;
      int cs = ((lin & 7) ^ (row & 7)) * 8;
      glds16(Bb + (size_t)row * 768 + cs, &sB[lin * 8]);
    }
    __syncthreads();
#pragma unroll
    for (int kk2 = 0; kk2 < 2; ++kk2) {
      bf16x8 af[4], bfg[8];
#pragma unroll
      for (int t = 0; t < 4; ++t) {
        int ra = wr * 64 + t * 16 + l16;
        af[t] = *(const bf16x8*)&sA[ra * 64 + (((kk2 * 4 + quad) ^ (ra & 7)) << 3)];
      }
#pragma unroll
      for (int t = 0; t < 8; ++t) {
        int rb = wc * 128 + t * 16 + l16;
        bfg[t] = *(const bf16x8*)&sB[rb * 64 + (((kk2 * 4 + quad) ^ (rb & 7)) << 3)];
      }
#pragma unroll
      for (int ti = 0; ti < 4; ++ti)
#pragma unroll
        for (int tj = 0; tj < 8; ++tj)
          acc[ti][tj] = __builtin_amdgcn_mfma_f32_16x16x32_bf16(af[ti], bfg[tj], acc[ti][tj], 0, 0, 0);
    }
  }

  // epilogue: C/D layout col=lane&15, row=quad*4+reg [m89-verified]
  const int wsel = by / 3;                    // 0:q 1:k 2:v
  const int nl0 = (by % 3) * 256 + wc * 128;  // col within [0,768)
  if (wsel == 2) {
#pragma unroll
    for (int ti = 0; ti < 4; ++ti)
#pragma unroll
      for (int tj = 0; tj < 8; ++tj) {
        int token = m0 + wr * 64 + ti * 16 + quad * 4;  // +r contiguous
        int nl = nl0 + tj * 16 + l16;
        int bh = (token >> 10) * 12 + (nl >> 6);
        short tmp[4];
#pragma unroll
        for (int r = 0; r < 4; ++r) tmp[r] = bfbits(acc[ti][tj][r]);
        *(uint2*)(vt + (size_t)bh * 65536 + (size_t)(nl & 63) * 1024 + (token & 1023)) =
            *(const uint2*)tmp;
      }
  } else {
    short* C = wsel ? k : q;
    const float sc = wsel ? 1.0f : 0.1803368801111244f;  // q: 0.125*log2(e)
#pragma unroll
    for (int ti = 0; ti < 4; ++ti)
#pragma unroll
      for (int tj = 0; tj < 8; ++tj)
#pragma unroll
        for (int r = 0; r < 4; ++r) {
          int row = m0 + wr * 64 + ti * 16 + quad * 4 + r;
          int nl = nl0 + tj * 16 + l16;
          C[(size_t)row * 768 + nl] = bfbits(acc[ti][tj][r] * sc);
        }
  }
}

// --------------------------------------------------------------------------
// Flash attention: block = (b,h) x 64 q-rows, grid 1536 (XCD remap: idx%96=bh).
// Single-buffered K/V (LDS 24KB -> 6 blocks/CU). Wave w owns q-rows w*16+l16.
// S' = K Q'^T; P = exp2(S') in regs; paired-tile PV. vect aliases q.
// --------------------------------------------------------------------------
__global__ __launch_bounds__(256) void attn_kernel(
    const short* __restrict__ q, const short* __restrict__ k,
    const short* __restrict__ vt, short* __restrict__ vect) {
  const int bh = blockIdx.x % 96;
  const int qt = blockIdx.x / 96;
  const int b = bh / 12, h = bh % 12;
  const int m0 = qt * 64;
  const int tid = threadIdx.x;
  const int w = tid >> 6, lane = tid & 63, l16 = lane & 15, quad = lane >> 4;

  __shared__ short sQ[64 * 64];
  __shared__ short sK[64 * 64];
  __shared__ short sVt[64 * 64];

  const size_t base = (size_t)b * 786432 + (size_t)h * 64;
  const size_t vbase = (size_t)bh * 65536;

  // stage Q once (512 chunks)
#pragma unroll
  for (int p = 0; p < 2; ++p) {
    int lin = (w * 2 + p) * 64 + lane;
    int row = lin >> 3;
    int cs = ((lin & 7) ^ (row & 7)) * 8;
    glds16(q + base + (size_t)(m0 + row) * 768 + cs, &sQ[lin * 8]);
  }
  __syncthreads();
  bf16x8 bq[2];
#pragma unroll
  for (int kk = 0; kk < 2; ++kk) {
    int row = w * 16 + l16;
    bq[kk] = *(const bf16x8*)&sQ[row * 64 + (((kk * 4 + quad) ^ (row & 7)) << 3)];
  }

  f32x4 l4 = (f32x4){0.f, 0.f, 0.f, 0.f};
  f32x4 oacc[4];
#pragma unroll
  for (int td = 0; td < 4; ++td) oacc[td] = (f32x4){0.f, 0.f, 0.f, 0.f};

  for (int j0 = 0; j0 < 1024; j0 += 64) {
    __syncthreads();  // prior iter's sK/sVt reads retired (also covers bq reads)
#pragma unroll
    for (int p = 0; p < 2; ++p) {
      int lin = (w * 2 + p) * 64 + lane;
      int row = lin >> 3;
      int cs = ((lin & 7) ^ (row & 7)) * 8;
      glds16(k + base + (size_t)(j0 + row) * 768 + cs, &sK[lin * 8]);
      glds16(vt + vbase + (size_t)row * 1024 + j0 + cs, &sVt[lin * 8]);
    }
    __syncthreads();

    // S' tiles: ti-th tile rows j=ti*16+quad*4+r, col i=l16
    f32x4 s[4];
#pragma unroll
    for (int ti = 0; ti < 4; ++ti) s[ti] = (f32x4){0.f, 0.f, 0.f, 0.f};
#pragma unroll
    for (int kk = 0; kk < 2; ++kk)
#pragma unroll
      for (int ti = 0; ti < 4; ++ti) {
        int row = ti * 16 + l16;
        bf16x8 a = *(const bf16x8*)&sK[row * 64 + (((kk * 4 + quad) ^ (row & 7)) << 3)];
        s[ti] = __builtin_amdgcn_mfma_f32_16x16x32_bf16(a, bq[kk], s[ti], 0, 0, 0);
      }

    // P = exp2(S'); packed row-sum; HW packed bf16 convert
    bf16x4 pb[4];
#pragma unroll
    for (int ti = 0; ti < 4; ++ti) {
      f32x4 e;
      e[0] = fast_exp2(s[ti][0]);
      e[1] = fast_exp2(s[ti][1]);
      e[2] = fast_exp2(s[ti][2]);
      e[3] = fast_exp2(s[ti][3]);
      l4 += e;
      bf16x4 tb;
      tb[0] = (__bf16)e[0]; tb[1] = (__bf16)e[1];
      tb[2] = (__bf16)e[2]; tb[3] = (__bf16)e[3];
      pb[ti] = tb;
    }

    // O^T += V^T P^T (paired S^T tiles as B-frag)
#pragma unroll
    for (int t2 = 0; t2 < 2; ++t2) {
      union { bf16x4 h[2]; bf16x8 v; } bp;
      bp.h[0] = pb[2 * t2];
      bp.h[1] = pb[2 * t2 + 1];
#pragma unroll
      for (int td = 0; td < 4; ++td) {
        int row = td * 16 + l16;
        int o1 = t2 * 32 + quad * 4;
        int c1 = o1 >> 3, w1 = o1 & 7;
        int c2 = c1 + 2;
        union { uint2 u[2]; bf16x8 v; } tmp;
        tmp.u[0] = *(const uint2*)&sVt[row * 64 + ((c1 ^ (row & 7)) << 3) + w1];
        tmp.u[1] = *(const uint2*)&sVt[row * 64 + ((c2 ^ (row & 7)) << 3) + w1];
        oacc[td] = __builtin_amdgcn_mfma_f32_16x16x32_bf16(tmp.v, bp.v, oacc[td], 0, 0, 0);
      }
    }
  }

  // epilogue (writes exactly the q rows this block read -> alias safe)
  float l = (l4[0] + l4[1]) + (l4[2] + l4[3]);
  l += __shfl_xor(l, 16);
  l += __shfl_xor(l, 32);
  float inv = 1.0f / l;
  int i_tok = m0 + w * 16 + l16;
#pragma unroll
  for (int td = 0; td < 4; ++td) {
    short tmp[4];
#pragma unroll
    for (int r = 0; r < 4; ++r) tmp[r] = bfbits(oacc[td][r] * inv);
    *(uint2*)(vect + base + (size_t)i_tok * 768 + td * 16 + quad * 4) = *(const uint2*)tmp;
  }
}

// --------------------------------------------------------------------------
// Out projection: 64x128 tile (grid 128x6 = 768 blocks), pure glds, bf16 ops.
// --------------------------------------------------------------------------
__global__ __launch_bounds__(256) void gemm_out(
    const short* __restrict__ vect, const short* __restrict__ wob,
    float* __restrict__ out) {
  const int m0 = blockIdx.x * 64;
  const int n0 = blockIdx.y * 128;
  const int tid = threadIdx.x;
  const int w = tid >> 6, lane = tid & 63, l16 = lane & 15, quad = lane >> 4;
  const int wr = w >> 1, wc = w & 1;

  __shared__ short sA[64 * 64];
  __shared__ short sB[128 * 64];

  f32x4 acc[2][4];
#pragma unroll
  for (int i = 0; i < 2; ++i)
#pragma unroll
    for (int j = 0; j < 4; ++j) acc[i][j] = (f32x4){0.f, 0.f, 0.f, 0.f};

  for (int k0 = 0; k0 < 768; k0 += 64) {
    __syncthreads();
    const short* Ab = vect + (size_t)m0 * 768 + k0;
    const short* Bb = wob + (size_t)n0 * 768 + k0;
#pragma unroll
    for (int p = 0; p < 2; ++p) {
      int lin = (w * 2 + p) * 64 + lane;
      int row = lin >> 3;
      int cs = ((lin & 7) ^ (row & 7)) * 8;
      glds16(Ab + (size_t)row * 768 + cs, &sA[lin * 8]);
    }
#pragma unroll
    for (int p = 0; p < 4; ++p) {
      int lin = (w * 4 + p) * 64 + lane;
      int row = lin >> 3;
      int cs = ((lin & 7) ^ (row & 7)) * 8;
      glds16(Bb + (size_t)row * 768 + cs, &sB[lin * 8]);
    }
    __syncthreads();
#pragma unroll
    for (int kk2 = 0; kk2 < 2; ++kk2) {
      bf16x8 af[2], bfg[4];
#pragma unroll
      for (int t = 0; t < 2; ++t) {
        int ra = wr * 32 + t * 16 + l16;
        af[t] = *(const bf16x8*)&sA[ra * 64 + (((kk2 * 4 + quad) ^ (ra & 7)) << 3)];
      }
#pragma unroll
      for (int t = 0; t < 4; ++t) {
        int rb = wc * 64 + t * 16 + l16;
        bfg[t] = *(const bf16x8*)&sB[rb * 64 + (((kk2 * 4 + quad) ^ (rb & 7)) << 3)];
      }
#pragma unroll
      for (int ti = 0; ti < 2; ++ti)
#pragma unroll
        for (int tj = 0; tj < 4; ++tj)
          acc[ti][tj] = __builtin_amdgcn_mfma_f32_16x16x32_bf16(af[ti], bfg[tj], acc[ti][tj], 0, 0, 0);
    }
  }
#pragma unroll
  for (int ti = 0; ti < 2; ++ti)
#pragma unroll
    for (int tj = 0; tj < 4; ++tj)
#pragma unroll
      for (int r = 0; r < 4; ++r) {
        int row = m0 + wr * 32 + ti * 16 + quad * 4 + r;
        int col = n0 + wc * 64 + tj * 16 + l16;
        out[(size_t)row * 768 + col] = acc[ti][tj][r];
      }
}

// --------------------------------------------------------------------------
extern "C" void kernel_launch(void* const* d_in, const int* in_sizes, int n_in,
                              void* d_out, int out_size, void* d_ws, size_t ws_size,
                              hipStream_t stream) {
  const float* x  = (const float*)d_in[0];
  const float* Wq = (const float*)d_in[1];
  const float* Wk = (const float*)d_in[2];
  const float* Wv = (const float*)d_in[3];
  const float* Wo = (const float*)d_in[4];
  float* out = (float*)d_out;

  const size_t MN = (size_t)8192 * 768;
  short* q    = (short*)d_ws;      // attn output (vect) aliases q
  short* k    = q + MN;
  short* vt   = k + MN;            // per-head transposed V: [96][64][1024]
  short* vect = q;                 // alias (attn writes exactly its own q rows)
  short* wob  = vt + MN;           // bf16 Wo, survives through gemm_out

  short* xb   = (short*)d_out;     // scratch in d_out head (dead before gemm_out)
  short* wqkv = xb + MN;

  convert_kernel<<<1056, 256, 0, stream>>>(x, Wq, Wk, Wv, Wo, xb, wqkv, wob);
  gemm_qkv<<<dim3(64, 9), 256, 0, stream>>>(xb, wqkv, q, k, vt);
  attn_kernel<<<1536, 256, 0, stream>>>(q, k, vt, vect);
  gemm_out<<<dim3(128, 6), 256, 0, stream>>>(vect, wob, out);
}

// Round 10
// 192.833 us; speedup vs baseline: 1.1259x; 1.1259x over previous
//
#include <hip/hip_runtime.h>
#include <hip/hip_bf16.h>
#include <stdint.h>

// MetaAttention: x[8,1024,768] f32, Wq/Wk/Wv/Wo[768,768] f32 -> out[8,1024,768] f32
// Pipeline (4 kernels):
//   convert: x->xb, [Wq;Wk;Wv]->wqkv (d_out head scratch), Wo->wob (d_ws tail).
//   gemm_qkv: fused NT GEMM M=8192 N=2304 K=768, 128x128 tile, glds + XOR swizzle;
//             q pre-scaled by 0.125*log2(e); v stored per-head transposed vt.
//   attn: (b,h) x 64 q-rows per block (grid 1536, XCD remap); BJ=128 K/V tiles
//         (two 64-col compute halves per barrier-pair, s[] regs reused);
//         Q staged into sK space (frags hoisted to regs); LDS 32KB -> 5/CU;
//         S'=K Q'^T; P=exp2(S') in regs feeding PV B-frags; vect ALIASES q.
//   gemm_out: out = vect Wo^T, 64x128 tile (768 blocks), pure glds.
// d_ws (bf16): q/vect | k | vt | wob.

typedef __bf16 bf16x8 __attribute__((ext_vector_type(8)));
typedef __bf16 bf16x4 __attribute__((ext_vector_type(4)));
typedef float f32x4 __attribute__((ext_vector_type(4)));

#define GAS __attribute__((address_space(1)))
#define LAS __attribute__((address_space(3)))

__device__ __forceinline__ void glds16(const short* gp, short* lp) {
  __builtin_amdgcn_global_load_lds((const GAS void*)gp, (LAS void*)lp, 16, 0, 0);
}

__device__ __forceinline__ float fast_exp2(float x) {
#if __has_builtin(__builtin_amdgcn_exp2f)
  return __builtin_amdgcn_exp2f(x);
#else
  return __expf(x * 0.6931471805599453f);
#endif
}

__device__ __forceinline__ short bfbits(float f) {
  __bf16 b = (__bf16)f;                  // fptrunc RNE -> HW cvt
  union { __bf16 b; short s; } cv; cv.b = b;
  return cv.s;
}

__device__ __forceinline__ void stage8_f32(const float* __restrict__ src, short* dst) {
  float4 f0 = ((const float4*)src)[0];
  float4 f1 = ((const float4*)src)[1];
  bf16x8 t;
  t[0] = (__bf16)f0.x; t[1] = (__bf16)f0.y; t[2] = (__bf16)f0.z; t[3] = (__bf16)f0.w;
  t[4] = (__bf16)f1.x; t[5] = (__bf16)f1.y; t[6] = (__bf16)f1.z; t[7] = (__bf16)f1.w;
  *(bf16x8*)dst = t;
}

// --------------------------------------------------------------------------
// fp32 -> bf16 bulk conversion, flat exact grid: 1056 blocks x 1024 units.
// --------------------------------------------------------------------------
__global__ __launch_bounds__(256) void convert_kernel(
    const float* __restrict__ x, const float* __restrict__ Wq,
    const float* __restrict__ Wk, const float* __restrict__ Wv,
    const float* __restrict__ Wo,
    short* __restrict__ xb, short* __restrict__ wqkv, short* __restrict__ wob) {
  int u0 = blockIdx.x * 1024 + threadIdx.x;
#pragma unroll
  for (int i = 0; i < 4; ++i) {
    int u = u0 + i * 256;
    const float* src; short* dst;
    if (u < 786432) { src = x + (size_t)u * 8; dst = xb + (size_t)u * 8; }
    else if (u < 1007616) {
      int r = u - 786432;
      int wsel = r / 73728, off = r % 73728;
      const float* W = (wsel == 0) ? Wq : (wsel == 1) ? Wk : Wv;
      src = W + (size_t)off * 8;
      dst = wqkv + (size_t)r * 8;
    } else {
      int r = u - 1007616;
      src = Wo + (size_t)r * 8; dst = wob + (size_t)r * 8;
    }
    stage8_f32(src, dst);
  }
}

// --------------------------------------------------------------------------
// Fused QKV NT GEMM, 128x128 tile, BK=64, glds + XOR chunk swizzle (round-7).
// q output pre-scaled by 0.125*log2(e); v stored per-head transposed.
// --------------------------------------------------------------------------
__global__ __launch_bounds__(256) void gemm_qkv(
    const short* __restrict__ xb, const short* __restrict__ wqkv,
    short* __restrict__ q, short* __restrict__ k, short* __restrict__ vt) {
  const int m0 = blockIdx.x * 128;
  const int by = blockIdx.y;
  const int n0g = by * 128;
  const int tid = threadIdx.x;
  const int w = tid >> 6, lane = tid & 63, l16 = lane & 15, quad = lane >> 4;
  const int wr = w >> 1, wc = w & 1;

  __shared__ short sA[128 * 64];
  __shared__ short sB[128 * 64];

  f32x4 acc[4][4];
#pragma unroll
  for (int i = 0; i < 4; ++i)
#pragma unroll
    for (int j = 0; j < 4; ++j) acc[i][j] = (f32x4){0.f, 0.f, 0.f, 0.f};

  for (int k0 = 0; k0 < 768; k0 += 64) {
    __syncthreads();
    const short* Ab = xb + (size_t)m0 * 768 + k0;
    const short* Bb = wqkv + (size_t)n0g * 768 + k0;
#pragma unroll
    for (int p = 0; p < 4; ++p) {
      int lin = (w * 4 + p) * 64 + lane;
      int row = lin >> 3;
      int cs = ((lin & 7) ^ (row & 7)) * 8;
      glds16(Ab + (size_t)row * 768 + cs, &sA[lin * 8]);
      glds16(Bb + (size_t)row * 768 + cs, &sB[lin * 8]);
    }
    __syncthreads();
#pragma unroll
    for (int kk2 = 0; kk2 < 2; ++kk2) {
      bf16x8 af[4], bfg[4];
#pragma unroll
      for (int t = 0; t < 4; ++t) {
        int ra = wr * 64 + t * 16 + l16;
        af[t] = *(const bf16x8*)&sA[ra * 64 + (((kk2 * 4 + quad) ^ (ra & 7)) << 3)];
        int rb = wc * 64 + t * 16 + l16;
        bfg[t] = *(const bf16x8*)&sB[rb * 64 + (((kk2 * 4 + quad) ^ (rb & 7)) << 3)];
      }
#pragma unroll
      for (int ti = 0; ti < 4; ++ti)
#pragma unroll
        for (int tj = 0; tj < 4; ++tj)
          acc[ti][tj] = __builtin_amdgcn_mfma_f32_16x16x32_bf16(af[ti], bfg[tj], acc[ti][tj], 0, 0, 0);
    }
  }

  const int wsel = by / 6;                    // 0:q 1:k 2:v
  const int nl0 = (by % 6) * 128 + wc * 64;
  if (wsel == 2) {
#pragma unroll
    for (int ti = 0; ti < 4; ++ti)
#pragma unroll
      for (int tj = 0; tj < 4; ++tj) {
        int token = m0 + wr * 64 + ti * 16 + quad * 4;  // +r contiguous
        int nl = nl0 + tj * 16 + l16;
        int bh = (token >> 10) * 12 + (nl >> 6);
        short tmp[4];
#pragma unroll
        for (int r = 0; r < 4; ++r) tmp[r] = bfbits(acc[ti][tj][r]);
        *(uint2*)(vt + (size_t)bh * 65536 + (size_t)(nl & 63) * 1024 + (token & 1023)) =
            *(const uint2*)tmp;
      }
  } else {
    short* C = wsel ? k : q;
    const float sc = wsel ? 1.0f : 0.1803368801111244f;  // q: 0.125*log2(e)
#pragma unroll
    for (int ti = 0; ti < 4; ++ti)
#pragma unroll
      for (int tj = 0; tj < 4; ++tj)
#pragma unroll
        for (int r = 0; r < 4; ++r) {
          int row = m0 + wr * 64 + ti * 16 + quad * 4 + r;
          int nl = nl0 + tj * 16 + l16;
          C[(size_t)row * 768 + nl] = bfbits(acc[ti][tj][r] * sc);
        }
  }
}

// --------------------------------------------------------------------------
// Flash attention: block = (b,h) x 64 q-rows, grid 1536 (XCD remap: idx%96=bh).
// BJ=128: per barrier-pair stage K[128x64] + V^T[64x128]; two 64-col compute
// halves reuse s[] regs. Q staged into sK space (frags->regs). LDS 32KB.
// S' = K Q'^T; P = exp2(S') in regs; paired-tile PV. vect aliases q.
// --------------------------------------------------------------------------
__global__ __launch_bounds__(256) void attn_kernel(
    const short* __restrict__ q, const short* __restrict__ k,
    const short* __restrict__ vt, short* __restrict__ vect) {
  const int bh = blockIdx.x % 96;
  const int qt = blockIdx.x / 96;
  const int b = bh / 12, h = bh % 12;
  const int m0 = qt * 64;
  const int tid = threadIdx.x;
  const int w = tid >> 6, lane = tid & 63, l16 = lane & 15, quad = lane >> 4;

  __shared__ short sK[128 * 64];   // K tile; also hosts Q during prologue
  __shared__ short sVt[64 * 128];  // V^T tile [d][j], 16 chunks/row

  const size_t base = (size_t)b * 786432 + (size_t)h * 64;
  const size_t vbase = (size_t)bh * 65536;

  // prologue: stage Q (64x64) into sK head, hoist fragments to registers
#pragma unroll
  for (int p = 0; p < 2; ++p) {
    int lin = (w * 2 + p) * 64 + lane;
    int row = lin >> 3;
    int cs = ((lin & 7) ^ (row & 7)) * 8;
    glds16(q + base + (size_t)(m0 + row) * 768 + cs, &sK[lin * 8]);
  }
  __syncthreads();
  bf16x8 bq[2];
#pragma unroll
  for (int kk = 0; kk < 2; ++kk) {
    int row = w * 16 + l16;
    bq[kk] = *(const bf16x8*)&sK[row * 64 + (((kk * 4 + quad) ^ (row & 7)) << 3)];
  }

  f32x4 l4 = (f32x4){0.f, 0.f, 0.f, 0.f};
  f32x4 oacc[4];
#pragma unroll
  for (int td = 0; td < 4; ++td) oacc[td] = (f32x4){0.f, 0.f, 0.f, 0.f};

  for (int j0 = 0; j0 < 1024; j0 += 128) {
    __syncthreads();  // prior reads retired (incl. bq prologue reads on iter 0)
    // stage K: 128 rows x 64 cols, 1024 chunks (4/thread), 8-chunk rows
#pragma unroll
    for (int p = 0; p < 4; ++p) {
      int lin = (w * 4 + p) * 64 + lane;
      int row = lin >> 3;
      int cs = ((lin & 7) ^ (row & 7)) * 8;
      glds16(k + base + (size_t)(j0 + row) * 768 + cs, &sK[lin * 8]);
    }
    // stage V^T: 64 rows x 128 cols, 1024 chunks (4/thread), 16-chunk rows
#pragma unroll
    for (int p = 0; p < 4; ++p) {
      int lin = (w * 4 + p) * 64 + lane;
      int row = lin >> 4;
      int c = lin & 15;
      int cs = (c ^ (row & 15)) * 8;
      glds16(vt + vbase + (size_t)row * 1024 + j0 + cs, &sVt[lin * 8]);
    }
    __syncthreads();

#pragma unroll
    for (int jh = 0; jh < 2; ++jh) {
      // S' tiles: rows j = jh*64 + ti*16 + quad*4+r, col i=l16
      f32x4 s[4];
#pragma unroll
      for (int ti = 0; ti < 4; ++ti) s[ti] = (f32x4){0.f, 0.f, 0.f, 0.f};
#pragma unroll
      for (int kk = 0; kk < 2; ++kk)
#pragma unroll
        for (int ti = 0; ti < 4; ++ti) {
          int row = jh * 64 + ti * 16 + l16;
          bf16x8 a = *(const bf16x8*)&sK[row * 64 + (((kk * 4 + quad) ^ (row & 7)) << 3)];
          s[ti] = __builtin_amdgcn_mfma_f32_16x16x32_bf16(a, bq[kk], s[ti], 0, 0, 0);
        }

      // P = exp2(S'); packed row-sum; HW packed bf16 convert
      bf16x4 pb[4];
#pragma unroll
      for (int ti = 0; ti < 4; ++ti) {
        f32x4 e;
        e[0] = fast_exp2(s[ti][0]);
        e[1] = fast_exp2(s[ti][1]);
        e[2] = fast_exp2(s[ti][2]);
        e[3] = fast_exp2(s[ti][3]);
        l4 += e;
        bf16x4 tb;
        tb[0] = (__bf16)e[0]; tb[1] = (__bf16)e[1];
        tb[2] = (__bf16)e[2]; tb[3] = (__bf16)e[3];
        pb[ti] = tb;
      }

      // O^T += V^T P^T (paired S^T tiles as B-frag)
#pragma unroll
      for (int t2 = 0; t2 < 2; ++t2) {
        union { bf16x4 hh[2]; bf16x8 v; } bp;
        bp.hh[0] = pb[2 * t2];
        bp.hh[1] = pb[2 * t2 + 1];
#pragma unroll
        for (int td = 0; td < 4; ++td) {
          int row = td * 16 + l16;
          int o1 = jh * 64 + t2 * 32 + quad * 4;
          int c1 = o1 >> 3, w1 = o1 & 7;
          int c2 = c1 + 2;
          union { uint2 u[2]; bf16x8 v; } tmp;
          tmp.u[0] = *(const uint2*)&sVt[row * 128 + ((c1 ^ (row & 15)) << 3) + w1];
          tmp.u[1] = *(const uint2*)&sVt[row * 128 + ((c2 ^ (row & 15)) << 3) + w1];
          oacc[td] = __builtin_amdgcn_mfma_f32_16x16x32_bf16(tmp.v, bp.v, oacc[td], 0, 0, 0);
        }
      }
    }
  }

  // epilogue (writes exactly the q rows this block read -> alias safe)
  float l = (l4[0] + l4[1]) + (l4[2] + l4[3]);
  l += __shfl_xor(l, 16);
  l += __shfl_xor(l, 32);
  float inv = 1.0f / l;
  int i_tok = m0 + w * 16 + l16;
#pragma unroll
  for (int td = 0; td < 4; ++td) {
    short tmp[4];
#pragma unroll
    for (int r = 0; r < 4; ++r) tmp[r] = bfbits(oacc[td][r] * inv);
    *(uint2*)(vect + base + (size_t)i_tok * 768 + td * 16 + quad * 4) = *(const uint2*)tmp;
  }
}

// --------------------------------------------------------------------------
// Out projection: 64x128 tile (grid 128x6 = 768 blocks), pure glds, bf16 ops.
// --------------------------------------------------------------------------
__global__ __launch_bounds__(256) void gemm_out(
    const short* __restrict__ vect, const short* __restrict__ wob,
    float* __restrict__ out) {
  const int m0 = blockIdx.x * 64;
  const int n0 = blockIdx.y * 128;
  const int tid = threadIdx.x;
  const int w = tid >> 6, lane = tid & 63, l16 = lane & 15, quad = lane >> 4;
  const int wr = w >> 1, wc = w & 1;

  __shared__ short sA[64 * 64];
  __shared__ short sB[128 * 64];

  f32x4 acc[2][4];
#pragma unroll
  for (int i = 0; i < 2; ++i)
#pragma unroll
    for (int j = 0; j < 4; ++j) acc[i][j] = (f32x4){0.f, 0.f, 0.f, 0.f};

  for (int k0 = 0; k0 < 768; k0 += 64) {
    __syncthreads();
    const short* Ab = vect + (size_t)m0 * 768 + k0;
    const short* Bb = wob + (size_t)n0 * 768 + k0;
#pragma unroll
    for (int p = 0; p < 2; ++p) {
      int lin = (w * 2 + p) * 64 + lane;
      int row = lin >> 3;
      int cs = ((lin & 7) ^ (row & 7)) * 8;
      glds16(Ab + (size_t)row * 768 + cs, &sA[lin * 8]);
    }
#pragma unroll
    for (int p = 0; p < 4; ++p) {
      int lin = (w * 4 + p) * 64 + lane;
      int row = lin >> 3;
      int cs = ((lin & 7) ^ (row & 7)) * 8;
      glds16(Bb + (size_t)row * 768 + cs, &sB[lin * 8]);
    }
    __syncthreads();
#pragma unroll
    for (int kk2 = 0; kk2 < 2; ++kk2) {
      bf16x8 af[2], bfg[4];
#pragma unroll
      for (int t = 0; t < 2; ++t) {
        int ra = wr * 32 + t * 16 + l16;
        af[t] = *(const bf16x8*)&sA[ra * 64 + (((kk2 * 4 + quad) ^ (ra & 7)) << 3)];
      }
#pragma unroll
      for (int t = 0; t < 4; ++t) {
        int rb = wc * 64 + t * 16 + l16;
        bfg[t] = *(const bf16x8*)&sB[rb * 64 + (((kk2 * 4 + quad) ^ (rb & 7)) << 3)];
      }
#pragma unroll
      for (int ti = 0; ti < 2; ++ti)
#pragma unroll
        for (int tj = 0; tj < 4; ++tj)
          acc[ti][tj] = __builtin_amdgcn_mfma_f32_16x16x32_bf16(af[ti], bfg[tj], acc[ti][tj], 0, 0, 0);
    }
  }
#pragma unroll
  for (int ti = 0; ti < 2; ++ti)
#pragma unroll
    for (int tj = 0; tj < 4; ++tj)
#pragma unroll
      for (int r = 0; r < 4; ++r) {
        int row = m0 + wr * 32 + ti * 16 + quad * 4 + r;
        int col = n0 + wc * 64 + tj * 16 + l16;
        out[(size_t)row * 768 + col] = acc[ti][tj][r];
      }
}

// --------------------------------------------------------------------------
extern "C" void kernel_launch(void* const* d_in, const int* in_sizes, int n_in,
                              void* d_out, int out_size, void* d_ws, size_t ws_size,
                              hipStream_t stream) {
  const float* x  = (const float*)d_in[0];
  const float* Wq = (const float*)d_in[1];
  const float* Wk = (const float*)d_in[2];
  const float* Wv = (const float*)d_in[3];
  const float* Wo = (const float*)d_in[4];
  float* out = (float*)d_out;

  const size_t MN = (size_t)8192 * 768;
  short* q    = (short*)d_ws;      // attn output (vect) aliases q
  short* k    = q + MN;
  short* vt   = k + MN;            // per-head transposed V: [96][64][1024]
  short* vect = q;                 // alias (attn writes exactly its own q rows)
  short* wob  = vt + MN;           // bf16 Wo, survives through gemm_out

  short* xb   = (short*)d_out;     // scratch in d_out head (dead before gemm_out)
  short* wqkv = xb + MN;

  convert_kernel<<<1056, 256, 0, stream>>>(x, Wq, Wk, Wv, Wo, xb, wqkv, wob);
  gemm_qkv<<<dim3(64, 18), 256, 0, stream>>>(xb, wqkv, q, k, vt);
  attn_kernel<<<1536, 256, 0, stream>>>(q, k, vt, vect);
  gemm_out<<<dim3(128, 6), 256, 0, stream>>>(vect, wob, out);
}